// Round 5
// baseline (146.531 us; speedup 1.0000x reference)
//
#include <hip/hip_runtime.h>
#include <hip/hip_bf16.h>

// GAT layer: B=2, N=2048, C_IN=128, H=16, c=8.
// E(i,j) = exp(lrelu(lp_i+lc_j))*2^-12 = max(P1_i*Q1_j, P2_i*Q2_j) & adjmask (f16).
// Aggregation: mfma_f32_16x16x32_f16; B-operand = [h feats | ones buffer].
// Round 19: full-j attention with real occupancy. Wave = 1 head x 16 i-rows x
// j=0..2047; denominator from ones-column -> divide in-register, write out
// directly (no partials/combine). 1024 blocks x 256 thr = 4 blocks/CU,
// 4 waves/SIMD (launch_bounds(256,4)). LDS = 8 KB only: double-buffered
// adjacency byte-masks per 8-chunk step; staging = 4 float4/thread (16 VGPR),
// issued at step start (T14), converted+ds_write+barrier at step end ->
// ~64 KB/CU of adj loads in flight under compute. qI/hQ streams from global
// L2 (2-deep prefetch). XCD-chunked swizzle: the 4 head-group blocks sharing
// an i-stripe are consecutive logical ids on the same XCD; block hg writes
// the fused adj copy for steps {hg, hg+4}.
// d_out = [out: B*N*128][adj copy: B*N*N]

#define B_   2
#define N_   2048
#define CIN_ 128
#define H_   16

typedef _Float16 h2  __attribute__((ext_vector_type(2)));
typedef _Float16 v8h __attribute__((ext_vector_type(8)));
typedef float    v4f __attribute__((ext_vector_type(4)));

#define SC6 0.015625f   // 2^-6

__device__ inline h2 pk_f16(float a, float b) {
  return __builtin_bit_cast(h2, __builtin_amdgcn_cvt_pkrtz(a, b));
}
__device__ inline unsigned as_u32(h2 v) { return __builtin_bit_cast(unsigned, v); }
__device__ inline h2 as_h2(unsigned u) { return __builtin_bit_cast(h2, u); }

// 4 adjacency floats (exactly 0.0/1.0) -> 4 mask bytes 0x00/0xFF, j0 in byte0.
__device__ inline unsigned mask4(float4 f) {
  unsigned r = (unsigned)f.x | ((unsigned)f.y << 8) |
               ((unsigned)f.z << 16) | ((unsigned)f.w << 24);
  return (r << 8) - r;   // per-byte 0x01 -> 0xFF
}

__global__ __launch_bounds__(128) void proj_kernel(
    const float* __restrict__ nf, const float* __restrict__ W,
    const float* __restrict__ bias, const float* __restrict__ a,
    unsigned* __restrict__ hQ, unsigned* __restrict__ qI,
    float* __restrict__ lpT, unsigned* __restrict__ ones) {
  const int row0 = blockIdx.x * 4;       // 4 consecutive rows (same batch)
  const int t    = threadIdx.x;          // output column 0..127
  if (blockIdx.x == 0) {                 // ones-buffer for B-operand cols 8..15
    ones[t] = 0x3C003C00u; ones[t + 128] = 0x3C003C00u;
    ones[t + 256] = 0x3C003C00u; ones[t + 384] = 0x3C003C00u;
  }
  __shared__ float sNf[4][CIN_];
  ((float4*)&sNf[0][0])[t] = ((const float4*)(nf + (long)row0 * CIN_))[t];
  __syncthreads();
  float acc[4];
  const float bv = bias[t];
#pragma unroll
  for (int r = 0; r < 4; ++r) acc[r] = bv;
#pragma unroll 8
  for (int k = 0; k < CIN_; ++k) {
    const float w = W[k * 128 + t];
#pragma unroll
    for (int r = 0; r < 4; ++r) acc[r] = fmaf(sNf[r][k], w, acc[r]);
  }
  const int h = t >> 3, kc = t & 7;
  const int b = row0 >> 11, n0 = row0 & (N_ - 1);
  const int bh = b * H_ + h;
  const int cdw = n0 >> 1;               // j-pair dword index (2-aligned)
  uint2 hv;
  hv.x = as_u32(pk_f16(acc[0], acc[1]));
  hv.y = as_u32(pk_f16(acc[2], acc[3]));
  *(uint2*)(hQ + ((long)(bh * 8 + kc)) * (N_ / 2) + cdw) = hv;

  const float ap = a[h * 16 + kc], ac = a[h * 16 + 8 + kc];
  float lpv[4], lcv[4];
#pragma unroll
  for (int r = 0; r < 4; ++r) {
    float x = acc[r] * ap, y = acc[r] * ac;
#pragma unroll
    for (int s = 1; s < 8; s <<= 1) {
      x += __shfl_xor(x, s);
      y += __shfl_xor(y, s);
    }
    lpv[r] = x; lcv[r] = y;
  }
  if (kc == 0) {
    float4 l0 = {lpv[0], lpv[1], lpv[2], lpv[3]};
    *(float4*)(lpT + (long)bh * N_ + n0) = l0;
    uint2 q1, q2;
    q1.x = as_u32(pk_f16(__expf(lcv[0]) * SC6, __expf(lcv[1]) * SC6));
    q1.y = as_u32(pk_f16(__expf(lcv[2]) * SC6, __expf(lcv[3]) * SC6));
    q2.x = as_u32(pk_f16(__expf(0.2f * lcv[0]) * SC6, __expf(0.2f * lcv[1]) * SC6));
    q2.y = as_u32(pk_f16(__expf(0.2f * lcv[2]) * SC6, __expf(0.2f * lcv[3]) * SC6));
    // interleave: chunk(16 pairs)=32dw: [q1 quad0|q2 quad0|...|q1 quad3|q2 quad3]
    const int addr = bh * 2048 + (cdw >> 4) * 32 + ((cdw >> 2) & 3) * 8;
    const int off  = cdw & 3;            // 0 or 2
    *(uint2*)(qI + addr + off)     = q1;
    *(uint2*)(qI + addr + 4 + off) = q2;
  }
}

__global__ __launch_bounds__(256, 4) void attn_kernel(
    const float* __restrict__ adj, const unsigned* __restrict__ hQ,
    const unsigned* __restrict__ qI, const float* __restrict__ lpT,
    const unsigned* __restrict__ ones, float* __restrict__ out,
    float* __restrict__ adj_out) {
  // XCD-chunked swizzle (bijective, 1024 % 8 == 0): hardware round-robins
  // blockIdx%8 over XCDs; this remap gives each XCD a contiguous logical
  // range, so the 4 head-group blocks of one i-stripe (logical 4t..4t+3)
  // share one XCD's L2.
  const int L    = (blockIdx.x & 7) * 128 + (blockIdx.x >> 3);
  const int hg   = L & 3;                // head-group: heads hg*4 .. hg*4+3
  const int it   = (L >> 2) & 127;       // 16-row i-tile
  const int b    = L >> 9;
  const int i0   = it * 16;
  const int t    = threadIdx.x;          // 0..255
  const int w    = t >> 6;               // wave 0..3
  const int lane = t & 63;
  const int m    = lane & 15;            // A row / B col / D col
  const int q    = lane >> 4;            // k-quad
  const int h    = hg * 4 + w;           // this wave's head
  const int bh   = b * H_ + h;

  // masks: 2 bufs x [chl*64 + q*16 + m], uint2 = 8 j-cols. 8 KB.
  __shared__ uint2 sAm[1024];

  // staging decomposition: row tm = t&15, col-group cg = t>>4 (16 cols each);
  // step s covers cols [s*256, s*256+256).
  const int  tm = t & 15, cg = t >> 4;
  const int  chl = cg >> 1, qh = (cg & 1) * 2;     // sAm slot for this thread
  const long abase = ((long)(b * N_) + i0 + tm) * N_ + cg * 16;
  const bool owner_even = (hg == 0) | (hg == 1) | (hg == 2) | (hg == 3); // placate

  float4 f0, f1, f2, f3;                 // 16 VGPRs of staging
  auto STAGE_LOAD = [&](int ss) {
    const float* ap = adj + abase + ss * 256;
    f0 = *(const float4*)(ap);
    f1 = *(const float4*)(ap + 4);
    f2 = *(const float4*)(ap + 8);
    f3 = *(const float4*)(ap + 12);
  };
  auto STAGE_WRITE = [&](int ss) {
    const int buf = (ss & 1) * 512;
    uint2 mv0; mv0.x = mask4(f0); mv0.y = mask4(f1);
    uint2 mv1; mv1.x = mask4(f2); mv1.y = mask4(f3);
    sAm[buf + chl * 64 + qh * 16 + tm]       = mv0;
    sAm[buf + chl * 64 + (qh + 1) * 16 + tm] = mv1;
    if (hg == (ss & 3)) {                // fused adj copy, spread over blocks
      float* op = adj_out + abase + ss * 256;
      *(float4*)(op)      = f0;
      *(float4*)(op + 4)  = f1;
      *(float4*)(op + 8)  = f2;
      *(float4*)(op + 12) = f3;
    }
  };

  // per-row parent factors (rows i0+m)
  const float lp  = lpT[(long)bh * N_ + i0 + m];
  const float e1  = __expf(lp) * SC6, e2 = __expf(0.2f * lp) * SC6;
  const h2 P1 = pk_f16(e1, e1), P2 = pk_f16(e2, e2);

  // global Q/hQ streams (L2-hot), 2-deep prefetch
  const unsigned* qp = qI + bh * 2048 + q * 8;
  const unsigned hmask = (m < 8) ? ~0u : 0u;
  const unsigned* hp = (m < 8)
      ? hQ + ((long)(bh * 8 + m)) * (N_ / 2) + q * 4
      : ones + q * 4;

  uint4 bq1[2], bq2[2], bhq[2];
  bq1[0] = *(const uint4*)(qp);       bq2[0] = *(const uint4*)(qp + 4);
  bq1[1] = *(const uint4*)(qp + 32);  bq2[1] = *(const uint4*)(qp + 36);
  bhq[0] = *(const uint4*)(hp);
  bhq[1] = *(const uint4*)(hp + (16 & hmask));

  v4f acc = {0.f, 0.f, 0.f, 0.f};

  // prologue: stage step 0
  STAGE_LOAD(0);
  STAGE_WRITE(0);
  __syncthreads();

  for (int s = 0; s < 8; ++s) {
    if (s < 7) STAGE_LOAD(s + 1);        // issue early; consumed after compute
    const int buf = (s & 1) * 512;
#pragma unroll
    for (int cc = 0; cc < 8; ++cc) {
      const int ch = s * 8 + cc;
      const int p  = ch & 1;
      // prefetch ch+2 (overrun reads stay inside ws; discarded)
      const uint4 nq1 = *(const uint4*)(qp + (ch + 2) * 32);
      const uint4 nq2 = *(const uint4*)(qp + (ch + 2) * 32 + 4);
      const uint4 nhq = *(const uint4*)(hp + (((ch + 2) * 16) & hmask));

      const uint2 Mv = sAm[buf + cc * 64 + lane];
      const unsigned ma = __builtin_amdgcn_perm(Mv.x, Mv.x, 0x01010000u);
      const unsigned mb = __builtin_amdgcn_perm(Mv.x, Mv.x, 0x03030202u);
      const unsigned mc = __builtin_amdgcn_perm(Mv.y, Mv.y, 0x01010000u);
      const unsigned md = __builtin_amdgcn_perm(Mv.y, Mv.y, 0x03030202u);

      const uint4 q1 = bq1[p], q2 = bq2[p];
      const v8h bf = __builtin_bit_cast(v8h, bhq[p]);
      const uint4 af = {
        as_u32(__builtin_elementwise_max(P1 * as_h2(q1.x), P2 * as_h2(q2.x))) & ma,
        as_u32(__builtin_elementwise_max(P1 * as_h2(q1.y), P2 * as_h2(q2.y))) & mb,
        as_u32(__builtin_elementwise_max(P1 * as_h2(q1.z), P2 * as_h2(q2.z))) & mc,
        as_u32(__builtin_elementwise_max(P1 * as_h2(q1.w), P2 * as_h2(q2.w))) & md};
      acc = __builtin_amdgcn_mfma_f32_16x16x32_f16(
          __builtin_bit_cast(v8h, af), bf, acc, 0, 0, 0);

      bq1[p] = nq1; bq2[p] = nq2; bhq[p] = nhq;
    }
    if (s < 7) { STAGE_WRITE(s + 1); __syncthreads(); }
  }

  // D: col = m, row = q*4 + r (i-row offset). Denominator in col 8.
#pragma unroll
  for (int r = 0; r < 4; ++r) {
    const float sden = __shfl(acc[r], (lane & 48) | 8);
    if (m < 8) {
      const long gi = ((long)(b * N_ + i0 + q * 4 + r)) * H_ + h;
      out[gi * 8 + m] = acc[r] / sden;
    }
  }
  (void)owner_even;
}

extern "C" void kernel_launch(void* const* d_in, const int* in_sizes, int n_in,
                              void* d_out, int out_size, void* d_ws, size_t ws_size,
                              hipStream_t stream) {
  const float* nf   = (const float*)d_in[0];
  const float* adj  = (const float*)d_in[1];
  const float* W    = (const float*)d_in[2];
  const float* bias = (const float*)d_in[3];
  const float* a    = (const float*)d_in[4];

  float* out     = (float*)d_out;
  float* adj_out = out + (long)B_ * N_ * H_ * 8;    // 524288 offset

  unsigned* ws   = (unsigned*)d_ws;
  unsigned* hQ   = ws;                       // 262144 dw
  unsigned* qI   = ws + 262144;              // 65536 dw
  float*    lpT  = (float*)(ws + 327680);    // 65536 floats
  unsigned* ones = ws + 393216;              // 512 dw

  hipLaunchKernelGGL(proj_kernel, dim3(B_ * N_ / 4), dim3(128), 0, stream,
                     nf, W, bias, a, hQ, qI, lpT, ones);
  hipLaunchKernelGGL(attn_kernel, dim3(1024), dim3(256), 0,
                     stream, adj, hQ, qI, lpT, ones, out, adj_out);
}

// Round 6
// 128.609 us; speedup vs baseline: 1.1394x; 1.1394x over previous
//
#include <hip/hip_runtime.h>
#include <hip/hip_bf16.h>

// GAT layer: B=2, N=2048, C_IN=128, H=16, c=8.
// E(i,j) = exp(lrelu(lp_i+lc_j))*2^-12 = max(P1_i*Q1_j, P2_i*Q2_j) & adjmask (f16).
// Aggregation: mfma_f32_16x16x32_f16; B-operand = [h feats | ones buffer].
// Round 20: full-j attention, r16 economics, pinned pipeline.
// Wave = 1 head x 32 i-rows x full j (denominator in ones-col -> direct out,
// no partials/combine). Block = 4 heads (256 thr), grid 512 = 2 blocks/CU.
// LDS 48 KB: double-buffered per-j-quarter {sQ 8 KB (qI copy), sAm 16 KB
// (byte masks)}. One barrier per quarter. Staging for quarter q+1 issued in
// 4 sub-batches (16 VGPR) at chunks 0/4/8/12 of quarter q, written at
// 4/8/12/15; __builtin_amdgcn_sched_barrier(0) after each load batch pins
// the issue point (r19 showed the compiler otherwise sinks the loads:
// VGPR=36). launch_bounds(256,2) gives RA a 256-reg budget. hQ = 2-deep
// global prefetch issued BEFORE staging batches (older in vmcnt FIFO).
// adj_out copy fused into staging, spread over the 4 sibling head-blocks.
// d_out = [out: B*N*128][adj copy: B*N*N]

#define B_   2
#define N_   2048
#define CIN_ 128
#define H_   16

typedef _Float16 h2  __attribute__((ext_vector_type(2)));
typedef _Float16 v8h __attribute__((ext_vector_type(8)));
typedef float    v4f __attribute__((ext_vector_type(4)));

#define SC6 0.015625f   // 2^-6

__device__ inline h2 pk_f16(float a, float b) {
  return __builtin_bit_cast(h2, __builtin_amdgcn_cvt_pkrtz(a, b));
}
__device__ inline unsigned as_u32(h2 v) { return __builtin_bit_cast(unsigned, v); }
__device__ inline h2 as_h2(unsigned u) { return __builtin_bit_cast(h2, u); }

// 4 adjacency floats (exactly 0.0/1.0) -> 4 mask bytes 0x00/0xFF, j0 in byte0.
__device__ inline unsigned mask4(float4 f) {
  unsigned r = (unsigned)f.x | ((unsigned)f.y << 8) |
               ((unsigned)f.z << 16) | ((unsigned)f.w << 24);
  return (r << 8) - r;   // per-byte 0x01 -> 0xFF
}

__global__ __launch_bounds__(128) void proj_kernel(
    const float* __restrict__ nf, const float* __restrict__ W,
    const float* __restrict__ bias, const float* __restrict__ a,
    unsigned* __restrict__ hQ, unsigned* __restrict__ qI,
    float* __restrict__ lpT, unsigned* __restrict__ ones) {
  const int row0 = blockIdx.x * 4;       // 4 consecutive rows (same batch)
  const int t    = threadIdx.x;          // output column 0..127
  if (blockIdx.x == 0) {                 // ones-buffer for B-operand cols 8..15
    ones[t] = 0x3C003C00u; ones[t + 128] = 0x3C003C00u;
    ones[t + 256] = 0x3C003C00u; ones[t + 384] = 0x3C003C00u;
  }
  __shared__ float sNf[4][CIN_];
  ((float4*)&sNf[0][0])[t] = ((const float4*)(nf + (long)row0 * CIN_))[t];
  __syncthreads();
  float acc[4];
  const float bv = bias[t];
#pragma unroll
  for (int r = 0; r < 4; ++r) acc[r] = bv;
#pragma unroll 8
  for (int k = 0; k < CIN_; ++k) {
    const float w = W[k * 128 + t];
#pragma unroll
    for (int r = 0; r < 4; ++r) acc[r] = fmaf(sNf[r][k], w, acc[r]);
  }
  const int h = t >> 3, kc = t & 7;
  const int b = row0 >> 11, n0 = row0 & (N_ - 1);
  const int bh = b * H_ + h;
  const int cdw = n0 >> 1;               // j-pair dword index (2-aligned)
  uint2 hv;
  hv.x = as_u32(pk_f16(acc[0], acc[1]));
  hv.y = as_u32(pk_f16(acc[2], acc[3]));
  *(uint2*)(hQ + ((long)(bh * 8 + kc)) * (N_ / 2) + cdw) = hv;

  const float ap = a[h * 16 + kc], ac = a[h * 16 + 8 + kc];
  float lpv[4], lcv[4];
#pragma unroll
  for (int r = 0; r < 4; ++r) {
    float x = acc[r] * ap, y = acc[r] * ac;
#pragma unroll
    for (int s = 1; s < 8; s <<= 1) {
      x += __shfl_xor(x, s);
      y += __shfl_xor(y, s);
    }
    lpv[r] = x; lcv[r] = y;
  }
  if (kc == 0) {
    float4 l0 = {lpv[0], lpv[1], lpv[2], lpv[3]};
    *(float4*)(lpT + (long)bh * N_ + n0) = l0;
    uint2 q1, q2;
    q1.x = as_u32(pk_f16(__expf(lcv[0]) * SC6, __expf(lcv[1]) * SC6));
    q1.y = as_u32(pk_f16(__expf(lcv[2]) * SC6, __expf(lcv[3]) * SC6));
    q2.x = as_u32(pk_f16(__expf(0.2f * lcv[0]) * SC6, __expf(0.2f * lcv[1]) * SC6));
    q2.y = as_u32(pk_f16(__expf(0.2f * lcv[2]) * SC6, __expf(0.2f * lcv[3]) * SC6));
    // interleave: chunk(16 pairs)=32dw: [q1 quad0|q2 quad0|...|q1 quad3|q2 quad3]
    const int addr = bh * 2048 + (cdw >> 4) * 32 + ((cdw >> 2) & 3) * 8;
    const int off  = cdw & 3;            // 0 or 2
    *(uint2*)(qI + addr + off)     = q1;
    *(uint2*)(qI + addr + 4 + off) = q2;
  }
}

__global__ __launch_bounds__(256, 2) void attn_kernel(
    const float* __restrict__ adj, const unsigned* __restrict__ hQ,
    const unsigned* __restrict__ qI, const float* __restrict__ lpT,
    const unsigned* __restrict__ ones, float* __restrict__ out,
    float* __restrict__ adj_out) {
  // XCD-chunked swizzle (bijective, 512 % 8 == 0): the 4 sibling head-blocks
  // of one (b, i-tile) stripe get consecutive logical ids -> same XCD L2.
  const int L  = (blockIdx.x & 7) * 64 + (blockIdx.x >> 3);
  const int hg = L & 3;                  // head-group: heads hg*4 .. hg*4+3
  const int it = (L >> 2) & 63;          // 32-row i-tile
  const int b  = L >> 8;
  const int i0 = it * 32;
  const int t = threadIdx.x, w = t >> 6, lane = t & 63;
  const int m = lane & 15, q = lane >> 4;
  const int h = hg * 4 + w, bh = b * H_ + h;

  __shared__ unsigned sQ[2][2048];       // 16 KB: qI slice, 4 heads x 512 dw
  __shared__ uint2    sAm[2][2048];      // 32 KB: masks, idx=u*1024+ch*64+q*16+m

  // staging decomposition
  const int srow = t & 31, su = srow >> 4, smm = srow & 15;
  const int scg  = t >> 5;               // 0..7 (16-col groups)
  const long arow = ((long)(b * N_) + i0 + srow) * N_;
  const unsigned* qbase =
      qI + (long)(b * H_ + hg * 4 + w) * 2048 + lane * 8;

  float4 f0, f1, f2, f3;                 // 16 VGPR adj staging
  uint4  s0, s1;                         // 8 VGPR sQ staging

  auto SQ_LOAD = [&](int jqn) {
    const unsigned* sp = qbase + jqn * 512;
    s0 = *(const uint4*)(sp);
    s1 = *(const uint4*)(sp + 4);
  };
  auto SQ_WRITE = [&](int nb) {
    unsigned* dp = &sQ[nb][w * 512 + lane * 8];
    *(uint4*)(dp)     = s0;
    *(uint4*)(dp + 4) = s1;
  };
  auto ADJ_LOAD = [&](int jqn, int sb) {
    const float* ap = adj + arow + jqn * 512 + sb * 128 + scg * 16;
    f0 = *(const float4*)(ap);
    f1 = *(const float4*)(ap + 4);
    f2 = *(const float4*)(ap + 8);
    f3 = *(const float4*)(ap + 12);
  };
  auto ADJ_WRITE = [&](int jqn, int sb, int nb) {
    uint2 mva, mvb;
    mva.x = mask4(f0); mva.y = mask4(f1);
    mvb.x = mask4(f2); mvb.y = mask4(f3);
    const int col = sb * 128 + scg * 16;
    const int idx = su * 1024 + (col >> 5) * 64 + ((col & 31) >> 3) * 16 + smm;
    sAm[nb][idx]      = mva;
    sAm[nb][idx + 16] = mvb;
    if (hg == sb) {                      // fused adj copy, 1/4 per sibling
      float* op = adj_out + arow + jqn * 512 + col;
      *(float4*)(op)      = f0;
      *(float4*)(op + 4)  = f1;
      *(float4*)(op + 8)  = f2;
      *(float4*)(op + 12) = f3;
    }
  };

  // per-row parent factors (subtile 0: rows i0+m, subtile 1: rows i0+16+m)
  const float lpa = lpT[(long)bh * N_ + i0 + m];
  const float lpb = lpT[(long)bh * N_ + i0 + 16 + m];
  const float e1a = __expf(lpa) * SC6, e2a = __expf(0.2f * lpa) * SC6;
  const float e1b = __expf(lpb) * SC6, e2b = __expf(0.2f * lpb) * SC6;
  const h2 P1a = pk_f16(e1a, e1a), P2a = pk_f16(e2a, e2a);
  const h2 P1b = pk_f16(e1b, e1b), P2b = pk_f16(e2b, e2b);

  // hQ stream (L2-hot, 16-lane broadcast-coalesced), 2-deep prefetch
  const unsigned hmask = (m < 8) ? ~0u : 0u;
  const unsigned* hp = (m < 8)
      ? hQ + ((long)(bh * 8 + m)) * (N_ / 2) + q * 4
      : ones + q * 4;
  uint4 bhq[2];
  bhq[0] = *(const uint4*)(hp);
  bhq[1] = *(const uint4*)(hp + (16 & hmask));

  v4f acc0 = {0.f, 0.f, 0.f, 0.f};       // rows i0 .. i0+15
  v4f acc1 = {0.f, 0.f, 0.f, 0.f};       // rows i0+16 .. i0+31

  // prologue: stage quarter 0 into buffer 0
  SQ_LOAD(0);  ADJ_LOAD(0, 0);
  SQ_WRITE(0); ADJ_WRITE(0, 0, 0);
  ADJ_LOAD(0, 1); ADJ_WRITE(0, 1, 0);
  ADJ_LOAD(0, 2); ADJ_WRITE(0, 2, 0);
  ADJ_LOAD(0, 3); ADJ_WRITE(0, 3, 0);
  __syncthreads();

  for (int jq = 0; jq < 4; ++jq) {
    const int buf = jq & 1, nbuf = buf ^ 1;
    const unsigned* sqb = &sQ[buf][w * 512 + q * 8];
    const uint2*    smb = &sAm[buf][0];
#pragma unroll
    for (int cc = 0; cc < 16; ++cc) {
      const int p = cc & 1;              // (jq*16+cc)&1 == cc&1
      // hQ prefetch FIRST (older than staging in the vmcnt FIFO)
      const int gn = ((jq * 16 + cc + 2) & 63) * 16;
      const uint4 nhq = *(const uint4*)(hp + (gn & hmask));

      if (jq < 3) {                      // pipelined staging of quarter jq+1
        if (cc == 0) {
          SQ_LOAD(jq + 1); ADJ_LOAD(jq + 1, 0);
          __builtin_amdgcn_sched_barrier(0);
        } else if (cc == 4) {
          SQ_WRITE(nbuf); ADJ_WRITE(jq + 1, 0, nbuf); ADJ_LOAD(jq + 1, 1);
          __builtin_amdgcn_sched_barrier(0);
        } else if (cc == 8) {
          ADJ_WRITE(jq + 1, 1, nbuf); ADJ_LOAD(jq + 1, 2);
          __builtin_amdgcn_sched_barrier(0);
        } else if (cc == 12) {
          ADJ_WRITE(jq + 1, 2, nbuf); ADJ_LOAD(jq + 1, 3);
          __builtin_amdgcn_sched_barrier(0);
        } else if (cc == 15) {
          ADJ_WRITE(jq + 1, 3, nbuf);
        }
      }

      const uint4 q1 = *(const uint4*)(sqb + cc * 32);
      const uint4 q2 = *(const uint4*)(sqb + cc * 32 + 4);
      const uint2 Mv0 = smb[cc * 64 + lane];
      const uint2 Mv1 = smb[1024 + cc * 64 + lane];
      const unsigned m0a = __builtin_amdgcn_perm(Mv0.x, Mv0.x, 0x01010000u);
      const unsigned m0b = __builtin_amdgcn_perm(Mv0.x, Mv0.x, 0x03030202u);
      const unsigned m0c = __builtin_amdgcn_perm(Mv0.y, Mv0.y, 0x01010000u);
      const unsigned m0d = __builtin_amdgcn_perm(Mv0.y, Mv0.y, 0x03030202u);
      const unsigned m1a = __builtin_amdgcn_perm(Mv1.x, Mv1.x, 0x01010000u);
      const unsigned m1b = __builtin_amdgcn_perm(Mv1.x, Mv1.x, 0x03030202u);
      const unsigned m1c = __builtin_amdgcn_perm(Mv1.y, Mv1.y, 0x01010000u);
      const unsigned m1d = __builtin_amdgcn_perm(Mv1.y, Mv1.y, 0x03030202u);

      const h2 Q1x = as_h2(q1.x), Q1y = as_h2(q1.y), Q1z = as_h2(q1.z), Q1w = as_h2(q1.w);
      const h2 Q2x = as_h2(q2.x), Q2y = as_h2(q2.y), Q2z = as_h2(q2.z), Q2w = as_h2(q2.w);
      const v8h bf = __builtin_bit_cast(v8h, bhq[p]);

      const uint4 af0 = {
        as_u32(__builtin_elementwise_max(P1a * Q1x, P2a * Q2x)) & m0a,
        as_u32(__builtin_elementwise_max(P1a * Q1y, P2a * Q2y)) & m0b,
        as_u32(__builtin_elementwise_max(P1a * Q1z, P2a * Q2z)) & m0c,
        as_u32(__builtin_elementwise_max(P1a * Q1w, P2a * Q2w)) & m0d};
      acc0 = __builtin_amdgcn_mfma_f32_16x16x32_f16(
          __builtin_bit_cast(v8h, af0), bf, acc0, 0, 0, 0);
      const uint4 af1 = {
        as_u32(__builtin_elementwise_max(P1b * Q1x, P2b * Q2x)) & m1a,
        as_u32(__builtin_elementwise_max(P1b * Q1y, P2b * Q2y)) & m1b,
        as_u32(__builtin_elementwise_max(P1b * Q1z, P2b * Q2z)) & m1c,
        as_u32(__builtin_elementwise_max(P1b * Q1w, P2b * Q2w)) & m1d};
      acc1 = __builtin_amdgcn_mfma_f32_16x16x32_f16(
          __builtin_bit_cast(v8h, af1), bf, acc1, 0, 0, 0);

      bhq[p] = nhq;
    }
    __syncthreads();
  }

  // D: col = m, row = q*4 + r. Denominator in col 8 (ones-columns).
#pragma unroll
  for (int u = 0; u < 2; ++u) {
    const v4f av = u ? acc1 : acc0;
#pragma unroll
    for (int r = 0; r < 4; ++r) {
      const float sden = __shfl(av[r], (lane & 48) | 8);
      if (m < 8) {
        const long gi = ((long)(b * N_ + i0 + u * 16 + q * 4 + r)) * H_ + h;
        out[gi * 8 + m] = av[r] / sden;
      }
    }
  }
}

extern "C" void kernel_launch(void* const* d_in, const int* in_sizes, int n_in,
                              void* d_out, int out_size, void* d_ws, size_t ws_size,
                              hipStream_t stream) {
  const float* nf   = (const float*)d_in[0];
  const float* adj  = (const float*)d_in[1];
  const float* W    = (const float*)d_in[2];
  const float* bias = (const float*)d_in[3];
  const float* a    = (const float*)d_in[4];

  float* out     = (float*)d_out;
  float* adj_out = out + (long)B_ * N_ * H_ * 8;    // 524288 offset

  unsigned* ws   = (unsigned*)d_ws;
  unsigned* hQ   = ws;                       // 262144 dw
  unsigned* qI   = ws + 262144;              // 65536 dw
  float*    lpT  = (float*)(ws + 327680);    // 65536 floats
  unsigned* ones = ws + 393216;              // 512 dw

  hipLaunchKernelGGL(proj_kernel, dim3(B_ * N_ / 4), dim3(128), 0, stream,
                     nf, W, bias, a, hQ, qI, lpT, ones);
  hipLaunchKernelGGL(attn_kernel, dim3(512), dim3(256), 0,
                     stream, adj, hQ, qI, lpT, ones, out, adj_out);
}